// Round 8
// baseline (321.227 us; speedup 1.0000x reference)
//
#include <hip/hip_runtime.h>
#include <math.h>

#define H 12
#define S 1024
#define D 128
#define NROWS (H * S) // 12288

typedef __attribute__((ext_vector_type(8))) _Float16 f16x8; // 8 fp16 in 4 VGPRs
typedef __attribute__((ext_vector_type(4))) float f32x4;
typedef __attribute__((ext_vector_type(4))) int i32x4;

__device__ __forceinline__ short f2h(float f) { // RNE float->fp16, bits as short
    _Float16 h = (_Float16)f;
    return __builtin_bit_cast(short, h);
}
__device__ __forceinline__ float h2f(short s) {
    return (float)__builtin_bit_cast(_Float16, s);
}
__device__ __forceinline__ f16x8 fneg8(f16x8 v) { // packed sign flip
    i32x4 u = __builtin_bit_cast(i32x4, v);
    u ^= (int)0x80008000;
    return __builtin_bit_cast(f16x8, u);
}

// ---- workspace layout (BYTE offsets) ----
#define WS_QP_R   0ULL
#define WS_QP_I   6291456ULL
#define WS_KP_R   12582912ULL
#define WS_KP_I   15728640ULL
#define WS_VPT_R  18874368ULL
#define WS_VPT_I  22020096ULL
#define WS_GP_R   25165824ULL
#define WS_GP_I   28311552ULL
#define WS_ACAT_R 31457280ULL
#define WS_ACAT_I 37748736ULL
#define WS_LAM    44040192ULL
#define WS_SC     44040448ULL
#define W16_PER_HEAD   4194304ULL // 2*1024*1024*2B
#define STAT_PER_HEAD  16384ULL   // 2*1024*8B

// ============================================================
__global__ void lam_kernel(const float* __restrict__ lq1, const float* __restrict__ lk1,
                           const float* __restrict__ lq2, const float* __restrict__ lk2,
                           float* __restrict__ lam_out)
{
    int t = threadIdx.x; // 128 threads
    float p1 = lq1[t] * lk1[t];
    float p2 = lq2[t] * lk2[t];
    #pragma unroll
    for (int off = 32; off; off >>= 1) {
        p1 += __shfl_xor(p1, off);
        p2 += __shfl_xor(p2, off);
    }
    __shared__ float s1[2], s2[2];
    if ((t & 63) == 0) { s1[t >> 6] = p1; s2[t >> 6] = p2; }
    __syncthreads();
    if (t == 0) {
        float l1 = expf(s1[0] + s1[1]);
        float l2 = expf(s2[0] + s2[1]);
        float x = l1 - l2 + 0.3555090675909693f; // 0.8 - 0.6*exp(-0.3)
        lam_out[0] = 1.0f / (1.0f + expf(-x));
    }
}

// ============================================================
// ALL FOUR projections in ONE dispatch. grid = (192, 10), 64x64 tiles.
// (exact r1-proven kernel)
// ============================================================
__global__ __launch_bounds__(256) void proj_all(
    const float* __restrict__ q_r, const float* __restrict__ q_i,
    const float* __restrict__ k_r, const float* __restrict__ k_i,
    const float* __restrict__ v_r, const float* __restrict__ v_i,
    const float* __restrict__ pe_q_r, const float* __restrict__ pe_q_i,
    const float* __restrict__ pe_k_r, const float* __restrict__ pe_k_i,
    const float* __restrict__ qw_r, const float* __restrict__ qw_i,
    const float* __restrict__ qb_r, const float* __restrict__ qb_i,
    const float* __restrict__ kw_r, const float* __restrict__ kw_i,
    const float* __restrict__ kb_r, const float* __restrict__ kb_i,
    const float* __restrict__ vw_r, const float* __restrict__ vw_i,
    const float* __restrict__ vb_r, const float* __restrict__ vb_i,
    const float* __restrict__ gw_r, const float* __restrict__ gw_i,
    const float* __restrict__ gb_r, const float* __restrict__ gb_i,
    short* __restrict__ qp_r, short* __restrict__ qp_i,
    short* __restrict__ kp_r, short* __restrict__ kp_i,
    short* __restrict__ vpT_r, short* __restrict__ vpT_i,
    short* __restrict__ gp_r, short* __restrict__ gp_i)
{
    const int y = blockIdx.y;
    const float *xr, *xi, *wr, *wi, *br, *bi, *per = nullptr, *pei = nullptr;
    short *outr_, *outi_;
    int M, omode, col0;
    if (y < 4)      { xr = q_r; xi = q_i; wr = qw_r; wi = qw_i; br = qb_r; bi = qb_i;
                      per = pe_q_r; pei = pe_q_i; outr_ = qp_r; outi_ = qp_i;
                      M = 256; omode = 1; col0 = y * 64; }
    else if (y < 6) { xr = k_r; xi = k_i; wr = kw_r; wi = kw_i; br = kb_r; bi = kb_i;
                      per = pe_k_r; pei = pe_k_i; outr_ = kp_r; outi_ = kp_i;
                      M = 128; omode = 1; col0 = (y - 4) * 64; }
    else if (y < 8) { xr = v_r; xi = v_i; wr = vw_r; wi = vw_i; br = vb_r; bi = vb_i;
                      outr_ = vpT_r; outi_ = vpT_i;
                      M = 128; omode = 2; col0 = (y - 6) * 64; }
    else            { xr = q_r; xi = q_i; wr = gw_r; wi = gw_i; br = gb_r; bi = gb_i;
                      outr_ = gp_r; outi_ = gp_i;
                      M = 128; omode = 1; col0 = (y - 8) * 64; }

    __shared__ short As[64 * 72], Brs[64 * 72], Bis[64 * 72];
    const int t = threadIdx.x;
    const int row0 = blockIdx.x * 64;
    const int lane = t & 63, wid = t >> 6;
    const int wm = (wid >> 1) * 32, wn = (wid & 1) * 32;
    const int fm = lane & 15, fq = lane >> 4;
    f32x4 zero4 = {0.f, 0.f, 0.f, 0.f};
    f32x4 accr[2][2], acci[2][2];
    #pragma unroll
    for (int i = 0; i < 2; ++i)
        #pragma unroll
        for (int j = 0; j < 2; ++j) { accr[i][j] = zero4; acci[i][j] = zero4; }

    for (int c = 0; c < 4; ++c) {
        const bool hi = (c >= 2);
        const int kb = (c & 1) * 64;
        const float* Asrc = hi ? xi : xr;
        const float* Brsrc = hi ? wi : wr;
        const float* Bisrc = hi ? wr : wi;
        const float bsign = hi ? -1.0f : 1.0f;
        __syncthreads();
        #pragma unroll
        for (int it = 0; it < 4; ++it) {
            int lin = it * 256 + t;
            int r = lin >> 4, k4 = (lin & 15) * 4;
            float4 va = *(const float4*)&Asrc[(size_t)(row0 + r) * 128 + kb + k4];
            *(short4*)&As[r * 72 + k4] = make_short4(f2h(va.x), f2h(va.y), f2h(va.z), f2h(va.w));
            float4 vr = *(const float4*)&Brsrc[(size_t)(col0 + r) * 128 + kb + k4];
            *(short4*)&Brs[r * 72 + k4] = make_short4(f2h(bsign * vr.x), f2h(bsign * vr.y),
                                                      f2h(bsign * vr.z), f2h(bsign * vr.w));
            float4 vi = *(const float4*)&Bisrc[(size_t)(col0 + r) * 128 + kb + k4];
            *(short4*)&Bis[r * 72 + k4] = make_short4(f2h(vi.x), f2h(vi.y), f2h(vi.z), f2h(vi.w));
        }
        __syncthreads();
        #pragma unroll
        for (int ks = 0; ks < 64; ks += 32) {
            f16x8 bfr[2], bfi[2];
            #pragma unroll
            for (int j = 0; j < 2; ++j) {
                bfr[j] = *(const f16x8*)&Brs[(wn + j * 16 + fm) * 72 + ks + fq * 8];
                bfi[j] = *(const f16x8*)&Bis[(wn + j * 16 + fm) * 72 + ks + fq * 8];
            }
            #pragma unroll
            for (int i = 0; i < 2; ++i) {
                f16x8 a = *(const f16x8*)&As[(wm + i * 16 + fm) * 72 + ks + fq * 8];
                #pragma unroll
                for (int j = 0; j < 2; ++j) {
                    accr[i][j] = __builtin_amdgcn_mfma_f32_16x16x32_f16(a, bfr[j], accr[i][j], 0, 0, 0);
                    acci[i][j] = __builtin_amdgcn_mfma_f32_16x16x32_f16(a, bfi[j], acci[i][j], 0, 0, 0);
                }
            }
        }
    }
    #pragma unroll
    for (int i = 0; i < 2; ++i)
        #pragma unroll
        for (int j = 0; j < 2; ++j) {
            int colc = col0 + wn + j * 16 + fm;
            float bbr = br[colc], bbi = bi[colc];
            if (omode == 2) {
                int rb = row0 + wm + i * 16 + fq * 4;
                int hq = rb >> 10, sq = rb & 1023;
                short4 o_r4 = make_short4(f2h(accr[i][j][0] + bbr), f2h(accr[i][j][1] + bbr),
                                          f2h(accr[i][j][2] + bbr), f2h(accr[i][j][3] + bbr));
                short4 o_i4 = make_short4(f2h(acci[i][j][0] + bbi), f2h(acci[i][j][1] + bbi),
                                          f2h(acci[i][j][2] + bbi), f2h(acci[i][j][3] + bbi));
                size_t ob = ((size_t)(hq * 128 + colc)) * 1024 + sq;
                *(short4*)&outr_[ob] = o_r4;
                *(short4*)&outi_[ob] = o_i4;
            } else {
                #pragma unroll
                for (int reg = 0; reg < 4; ++reg) {
                    int rr = row0 + wm + i * 16 + fq * 4 + reg;
                    float o_r = accr[i][j][reg] + bbr;
                    float o_i = acci[i][j][reg] + bbi;
                    if (per) {
                        o_r += per[(size_t)rr * 128 + (colc & 127)];
                        o_i += pei[(size_t)rr * 128 + (colc & 127)];
                    }
                    outr_[(size_t)rr * M + colc] = f2h(o_r);
                    outi_[(size_t)rr * M + colc] = f2h(o_i);
                }
            }
        }
}

// ============================================================
// o-projection: fp16 gated input gp, fp32 weights, fp32 out. 64x64 tiles.
// (exact r1-proven kernel)
// ============================================================
__global__ __launch_bounds__(256) void oproj_mfma(
    const short* __restrict__ gp_r, const short* __restrict__ gp_i,
    const float* __restrict__ wr, const float* __restrict__ wi,
    const float* __restrict__ br, const float* __restrict__ bi,
    float* __restrict__ outr, float* __restrict__ outi)
{
    __shared__ short As[64 * 72], Brs[64 * 72], Bis[64 * 72];
    const int t = threadIdx.x;
    const int row0 = blockIdx.x * 64, col0 = blockIdx.y * 64;
    const int lane = t & 63, wid = t >> 6;
    const int wm = (wid >> 1) * 32, wn = (wid & 1) * 32;
    const int fm = lane & 15, fq = lane >> 4;
    f32x4 zero4 = {0.f, 0.f, 0.f, 0.f};
    f32x4 accr[2][2], acci[2][2];
    #pragma unroll
    for (int i = 0; i < 2; ++i)
        #pragma unroll
        for (int j = 0; j < 2; ++j) { accr[i][j] = zero4; acci[i][j] = zero4; }

    for (int c = 0; c < 4; ++c) {
        const bool hi = (c >= 2);
        const int kb = (c & 1) * 64;
        const short* Asrc = hi ? gp_i : gp_r;
        const float* Brsrc = hi ? wi : wr;
        const float* Bisrc = hi ? wr : wi;
        const float bsign = hi ? -1.0f : 1.0f;
        __syncthreads();
        #pragma unroll
        for (int it = 0; it < 4; ++it) {
            int lin = it * 256 + t;
            int r = lin >> 4, k4 = (lin & 15) * 4;
            *(short4*)&As[r * 72 + k4] = *(const short4*)&Asrc[(size_t)(row0 + r) * 128 + kb + k4];
            float4 vr = *(const float4*)&Brsrc[(size_t)(col0 + r) * 128 + kb + k4];
            *(short4*)&Brs[r * 72 + k4] = make_short4(f2h(bsign * vr.x), f2h(bsign * vr.y),
                                                      f2h(bsign * vr.z), f2h(bsign * vr.w));
            float4 vi = *(const float4*)&Bisrc[(size_t)(col0 + r) * 128 + kb + k4];
            *(short4*)&Bis[r * 72 + k4] = make_short4(f2h(vi.x), f2h(vi.y), f2h(vi.z), f2h(vi.w));
        }
        __syncthreads();
        #pragma unroll
        for (int ks = 0; ks < 64; ks += 32) {
            f16x8 bfr[2], bfi[2];
            #pragma unroll
            for (int j = 0; j < 2; ++j) {
                bfr[j] = *(const f16x8*)&Brs[(wn + j * 16 + fm) * 72 + ks + fq * 8];
                bfi[j] = *(const f16x8*)&Bis[(wn + j * 16 + fm) * 72 + ks + fq * 8];
            }
            #pragma unroll
            for (int i = 0; i < 2; ++i) {
                f16x8 a = *(const f16x8*)&As[(wm + i * 16 + fm) * 72 + ks + fq * 8];
                #pragma unroll
                for (int j = 0; j < 2; ++j) {
                    accr[i][j] = __builtin_amdgcn_mfma_f32_16x16x32_f16(a, bfr[j], accr[i][j], 0, 0, 0);
                    acci[i][j] = __builtin_amdgcn_mfma_f32_16x16x32_f16(a, bfi[j], acci[i][j], 0, 0, 0);
                }
            }
        }
    }
    #pragma unroll
    for (int i = 0; i < 2; ++i)
        #pragma unroll
        for (int j = 0; j < 2; ++j) {
            int colc = col0 + wn + j * 16 + fm;
            float bbr = br[colc], bbi = bi[colc];
            #pragma unroll
            for (int reg = 0; reg < 4; ++reg) {
                int rr = row0 + wm + i * 16 + fq * 4 + reg;
                outr[(size_t)rr * 128 + colc] = accr[i][j][reg] + bbr;
                outi[(size_t)rr * 128 + colc] = acci[i][j][reg] + bbi;
            }
        }
}

// ============================================================
// Scores (exact r1-proven): 64q x 128k tile, K-chunk 64, Q+Kt LDS-staged.
// ============================================================
__global__ __launch_bounds__(256) void score_mfma(
    const short* __restrict__ qp_r, const short* __restrict__ qp_i,
    const short* __restrict__ kp_r, const short* __restrict__ kp_i,
    short* __restrict__ w16, int h0)
{
    __shared__ short Qr[64 * 72], Qi[64 * 72], Kt[128 * 72];
    const int t = threadIdx.x;
    const int hh = blockIdx.z >> 1, map = blockIdx.z & 1;
    const int h = h0 + hh;
    const int q0 = blockIdx.x * 64, c0 = blockIdx.y * 128;
    const int lane = t & 63, wid = t >> 6;
    const int wm = (wid >> 1) * 32, wn = (wid & 1) * 64;
    const int fm = lane & 15, fq = lane >> 4;
    f32x4 zero4 = {0.f, 0.f, 0.f, 0.f};
    f32x4 sr[2][4], si[2][4];
    #pragma unroll
    for (int i = 0; i < 2; ++i)
        #pragma unroll
        for (int j = 0; j < 4; ++j) { sr[i][j] = zero4; si[i][j] = zero4; }

    for (int kb = 0; kb < 2; ++kb) {
        const int kbase = map * 128 + kb * 64;
        __syncthreads();
        #pragma unroll
        for (int i = 0; i < 4; ++i) {
            int lin = i * 256 + t;
            int r = lin >> 4, k4 = (lin & 15) * 4;
            size_t qb = (size_t)(h * S + q0 + r) * 256 + kbase + k4;
            *(short4*)&Qr[r * 72 + k4] = *(const short4*)&qp_r[qb];
            *(short4*)&Qi[r * 72 + k4] = *(const short4*)&qp_i[qb];
        }
        #pragma unroll
        for (int i = 0; i < 8; ++i) {
            int lin = i * 256 + t;
            int r = lin >> 4, k4 = (lin & 15) * 4;
            *(short4*)&Kt[r * 72 + k4] =
                *(const short4*)&kp_r[(size_t)(h * S + c0 + r) * 128 + kb * 64 + k4];
        }
        __syncthreads();
        f16x8 aR[2][2], aI[2][2]; // [ks][i]
        #pragma unroll
        for (int ks = 0; ks < 2; ++ks)
            #pragma unroll
            for (int i = 0; i < 2; ++i) {
                int ao = (wm + i * 16 + fm) * 72 + ks * 32 + fq * 8;
                aR[ks][i] = *(const f16x8*)&Qr[ao];
                aI[ks][i] = *(const f16x8*)&Qi[ao];
            }
        #pragma unroll
        for (int ks = 0; ks < 2; ++ks) {
            f16x8 b[4];
            #pragma unroll
            for (int j = 0; j < 4; ++j)
                b[j] = *(const f16x8*)&Kt[(wn + j * 16 + fm) * 72 + ks * 32 + fq * 8];
            #pragma unroll
            for (int i = 0; i < 2; ++i)
                #pragma unroll
                for (int j = 0; j < 4; ++j) {
                    sr[i][j] = __builtin_amdgcn_mfma_f32_16x16x32_f16(aR[ks][i], b[j], sr[i][j], 0, 0, 0);
                    si[i][j] = __builtin_amdgcn_mfma_f32_16x16x32_f16(aI[ks][i], b[j], si[i][j], 0, 0, 0);
                }
        }
        __syncthreads();
        #pragma unroll
        for (int i = 0; i < 8; ++i) {
            int lin = i * 256 + t;
            int r = lin >> 4, k4 = (lin & 15) * 4;
            *(short4*)&Kt[r * 72 + k4] =
                *(const short4*)&kp_i[(size_t)(h * S + c0 + r) * 128 + kb * 64 + k4];
        }
        __syncthreads();
        #pragma unroll
        for (int ks = 0; ks < 2; ++ks) {
            f16x8 b[4];
            #pragma unroll
            for (int j = 0; j < 4; ++j)
                b[j] = *(const f16x8*)&Kt[(wn + j * 16 + fm) * 72 + ks * 32 + fq * 8];
            f16x8 nR0 = fneg8(aR[ks][0]), nR1 = fneg8(aR[ks][1]);
            #pragma unroll
            for (int j = 0; j < 4; ++j) {
                sr[0][j] = __builtin_amdgcn_mfma_f32_16x16x32_f16(aI[ks][0], b[j], sr[0][j], 0, 0, 0);
                si[0][j] = __builtin_amdgcn_mfma_f32_16x16x32_f16(nR0, b[j], si[0][j], 0, 0, 0);
                sr[1][j] = __builtin_amdgcn_mfma_f32_16x16x32_f16(aI[ks][1], b[j], sr[1][j], 0, 0, 0);
                si[1][j] = __builtin_amdgcn_mfma_f32_16x16x32_f16(nR1, b[j], si[1][j], 0, 0, 0);
            }
        }
    }
    const float scale = 0.08838834764831845f;
    #pragma unroll
    for (int i = 0; i < 2; ++i)
        #pragma unroll
        for (int j = 0; j < 4; ++j) {
            int kcol = c0 + wn + j * 16 + fm;
            #pragma unroll
            for (int reg = 0; reg < 4; ++reg) {
                int q = q0 + wm + i * 16 + fq * 4 + reg;
                float r1 = sr[i][j][reg], I1 = si[i][j][reg];
                float m1 = sqrtf(fmaf(r1, r1, fmaf(I1, I1, 1e-8f))) * scale;
                w16[(((size_t)hh * 2 + map) * S + q) * S + kcol] = f2h(m1);
            }
        }
}

// ============================================================
// Per-row softmax STATS only: stats[row]=(max, 1/sum). (exact r1-proven)
// ============================================================
__global__ __launch_bounds__(256) void smstats(const short* __restrict__ w16,
                                               float2* __restrict__ stats)
{
    const short* row = w16 + (size_t)blockIdx.x * S;
    int t = threadIdx.x;
    short4 s = ((const short4*)row)[t];
    float f0 = h2f(s.x), f1 = h2f(s.y), f2v = h2f(s.z), f3 = h2f(s.w);
    float m = fmaxf(fmaxf(f0, f1), fmaxf(f2v, f3));
    #pragma unroll
    for (int off = 32; off; off >>= 1) m = fmaxf(m, __shfl_xor(m, off));
    __shared__ float redm[4], reds[4];
    int w = t >> 6;
    if ((t & 63) == 0) redm[w] = m;
    __syncthreads();
    m = fmaxf(fmaxf(redm[0], redm[1]), fmaxf(redm[2], redm[3]));
    float ssum = __expf(f0 - m) + __expf(f1 - m) + __expf(f2v - m) + __expf(f3 - m);
    #pragma unroll
    for (int off = 32; off; off >>= 1) ssum += __shfl_xor(ssum, off);
    if ((t & 63) == 0) reds[w] = ssum;
    __syncthreads();
    if (t == 0) {
        float total = reds[0] + reds[1] + reds[2] + reds[3];
        stats[blockIdx.x] = make_float2(m, 1.0f / total);
    }
}

// ============================================================
// AV: 32q x full 128d, both maps, ONE complex comp per block (blockIdx.y).
// (exact r1-proven)
// ============================================================
__global__ __launch_bounds__(256) void av_mfma(
    const short* __restrict__ w16, const float2* __restrict__ stats,
    const short* __restrict__ vpT_r, const short* __restrict__ vpT_i,
    short* __restrict__ acat_r, short* __restrict__ acat_i, int h0)
{
    __shared__ short W1[32 * 72], W2[32 * 72], Vc[128 * 72];
    const int t = threadIdx.x;
    const int hh = blockIdx.z, h = h0 + hh;
    const int comp = blockIdx.y;
    const int q0 = blockIdx.x * 32;
    const short* vpT = comp ? vpT_i : vpT_r;
    short* acat = comp ? acat_i : acat_r;
    const float2* st1 = stats + ((size_t)hh * 2 + 0) * S;
    const float2* st2 = stats + ((size_t)hh * 2 + 1) * S;
    const int lane = t & 63, wid = t >> 6;
    const int wm = (wid >> 1) * 16, wn = (wid & 1) * 64;
    const int fm = lane & 15, fq = lane >> 4;
    f32x4 zero4 = {0.f, 0.f, 0.f, 0.f};
    f32x4 a1[4], a2[4];
    #pragma unroll
    for (int j = 0; j < 4; ++j) { a1[j] = zero4; a2[j] = zero4; }

    for (int k0 = 0; k0 < S; k0 += 64) {
        __syncthreads();
        #pragma unroll
        for (int it = 0; it < 2; ++it) {
            int lin = it * 256 + t;
            int r = lin >> 4, k4 = (lin & 15) * 4;
            float2 s1v = st1[q0 + r];
            float2 s2v = st2[q0 + r];
            short4 m1 = *(const short4*)&w16[(((size_t)hh * 2 + 0) * S + q0 + r) * S + k0 + k4];
            short4 m2 = *(const short4*)&w16[(((size_t)hh * 2 + 1) * S + q0 + r) * S + k0 + k4];
            *(short4*)&W1[r * 72 + k4] = make_short4(
                f2h(__expf(h2f(m1.x) - s1v.x) * s1v.y), f2h(__expf(h2f(m1.y) - s1v.x) * s1v.y),
                f2h(__expf(h2f(m1.z) - s1v.x) * s1v.y), f2h(__expf(h2f(m1.w) - s1v.x) * s1v.y));
            *(short4*)&W2[r * 72 + k4] = make_short4(
                f2h(__expf(h2f(m2.x) - s2v.x) * s2v.y), f2h(__expf(h2f(m2.y) - s2v.x) * s2v.y),
                f2h(__expf(h2f(m2.z) - s2v.x) * s2v.y), f2h(__expf(h2f(m2.w) - s2v.x) * s2v.y));
        }
        #pragma unroll
        for (int it = 0; it < 8; ++it) {
            int lin = it * 256 + t;
            int dd = lin >> 4, k4 = (lin & 15) * 4;
            *(short4*)&Vc[dd * 72 + k4] = *(const short4*)&vpT[(size_t)(h * 128 + dd) * 1024 + k0 + k4];
        }
        __syncthreads();
        #pragma unroll
        for (int ks = 0; ks < 64; ks += 32) {
            f16x8 b[4];
            #pragma unroll
            for (int j = 0; j < 4; ++j)
                b[j] = *(const f16x8*)&Vc[(wn + j * 16 + fm) * 72 + ks + fq * 8];
            int wo = (wm + fm) * 72 + ks + fq * 8;
            f16x8 w1f = *(const f16x8*)&W1[wo];
            f16x8 w2f = *(const f16x8*)&W2[wo];
            #pragma unroll
            for (int j = 0; j < 4; ++j) {
                a1[j] = __builtin_amdgcn_mfma_f32_16x16x32_f16(w1f, b[j], a1[j], 0, 0, 0);
                a2[j] = __builtin_amdgcn_mfma_f32_16x16x32_f16(w2f, b[j], a2[j], 0, 0, 0);
            }
        }
    }
    #pragma unroll
    for (int j = 0; j < 4; ++j) {
        int d = wn + j * 16 + fm;
        #pragma unroll
        for (int reg = 0; reg < 4; ++reg) {
            int q = q0 + wm + fq * 4 + reg;
            size_t rowb = (size_t)(h * S + q) * 256;
            acat[rowb + d]       = f2h(a1[j][reg]);
            acat[rowb + 128 + d] = f2h(a2[j][reg]);
        }
    }
}

// ============================================================
// RMS over 256 complex + sub_w + (a1 - lam*a2) + complex gate.
// (exact r1-proven)
// ============================================================
__global__ __launch_bounds__(256) void rmsgate_kernel(
    const short* __restrict__ acat_r, const short* __restrict__ acat_i,
    const float* __restrict__ sub_w, const float* __restrict__ lam_ptr,
    short* __restrict__ gp_r, short* __restrict__ gp_i)
{
    int row = blockIdx.x;
    int t = threadIdx.x;
    float ar = h2f(acat_r[(size_t)row * 256 + t]);
    float ai = h2f(acat_i[(size_t)row * 256 + t]);
    float ss = fmaf(ar, ar, ai * ai);
    #pragma unroll
    for (int off = 32; off; off >>= 1) ss += __shfl_xor(ss, off);
    __shared__ float red[4];
    if ((t & 63) == 0) red[t >> 6] = ss;
    __syncthreads();
    float total = red[0] + red[1] + red[2] + red[3];
    float inv_rms = 1.0f / sqrtf(total * (1.0f / 256.0f) + 1e-5f);
    float sw = sub_w[t];
    __shared__ float Cr[256], Ci[256];
    Cr[t] = ar * inv_rms * sw;
    Ci[t] = ai * inv_rms * sw;
    __syncthreads();
    if (t < 128) {
        float lam = lam_ptr[0];
        float o_r = Cr[t] - lam * Cr[t + 128];
        float o_i = Ci[t] - lam * Ci[t + 128];
        float gr = h2f(gp_r[(size_t)row * 128 + t]);
        float gi = h2f(gp_i[(size_t)row * 128 + t]);
        gp_r[(size_t)row * 128 + t] = f2h(gr * o_r - gi * o_i);
        gp_i[(size_t)row * 128 + t] = f2h(gr * o_i + gi * o_r);
    }
}

// ============================================================
extern "C" void kernel_launch(void* const* d_in, const int* in_sizes, int n_in,
                              void* d_out, int out_size, void* d_ws, size_t ws_size,
                              hipStream_t stream)
{
    (void)in_sizes; (void)n_in; (void)out_size;
    const float* q_r    = (const float*)d_in[0];
    const float* q_i    = (const float*)d_in[1];
    const float* k_r    = (const float*)d_in[2];
    const float* k_i    = (const float*)d_in[3];
    const float* v_r    = (const float*)d_in[4];
    const float* v_i    = (const float*)d_in[5];
    const float* pe_q_r = (const float*)d_in[6];
    const float* pe_q_i = (const float*)d_in[7];
    const float* pe_k_r = (const float*)d_in[8];
    const float* pe_k_i = (const float*)d_in[9];
    const float* qw_r   = (const float*)d_in[10];
    const float* qw_i   = (const float*)d_in[11];
    const float* qb_r   = (const float*)d_in[12];
    const float* qb_i   = (const float*)d_in[13];
    const float* kw_r   = (const float*)d_in[14];
    const float* kw_i   = (const float*)d_in[15];
    const float* kb_r   = (const float*)d_in[16];
    const float* kb_i   = (const float*)d_in[17];
    const float* vw_r   = (const float*)d_in[18];
    const float* vw_i   = (const float*)d_in[19];
    const float* vb_r   = (const float*)d_in[20];
    const float* vb_i   = (const float*)d_in[21];
    const float* gw_r   = (const float*)d_in[22];
    const float* gw_i   = (const float*)d_in[23];
    const float* gb_r   = (const float*)d_in[24];
    const float* gb_i   = (const float*)d_in[25];
    const float* ow_r   = (const float*)d_in[26];
    const float* ow_i   = (const float*)d_in[27];
    const float* ob_r   = (const float*)d_in[28];
    const float* ob_i   = (const float*)d_in[29];
    const float* lq1    = (const float*)d_in[30];
    const float* lk1    = (const float*)d_in[31];
    const float* lq2    = (const float*)d_in[32];
    const float* lk2    = (const float*)d_in[33];
    const float* sub_w  = (const float*)d_in[34];

    char* ws = (char*)d_ws;
    short* qp_r   = (short*)(ws + WS_QP_R);
    short* qp_i   = (short*)(ws + WS_QP_I);
    short* kp_r   = (short*)(ws + WS_KP_R);
    short* kp_i   = (short*)(ws + WS_KP_I);
    short* vpT_r  = (short*)(ws + WS_VPT_R);
    short* vpT_i  = (short*)(ws + WS_VPT_I);
    short* gp_r   = (short*)(ws + WS_GP_R);
    short* gp_i   = (short*)(ws + WS_GP_I);
    short* acat_r = (short*)(ws + WS_ACAT_R);
    short* acat_i = (short*)(ws + WS_ACAT_I);
    float* lam    = (float*)(ws + WS_LAM);
    short* w16    = (short*)(ws + WS_SC);

    float* out_r = (float*)d_out;
    float* out_i = out_r + (size_t)NROWS * D;

    // head-chunking by workspace (graph-safe) — CAPPED AT 6 this round to
    // split the attention chain into 2 chunks: halves score/av durations so
    // the rocprof top-5 window reveals proj/oproj, and the total's delta vs
    // 296.7 measures per-dispatch-boundary cost (+3 boundaries).
    size_t avail = ws_size > WS_SC ? ws_size - WS_SC : 0;
    int nh_chunk = (int)(avail / (W16_PER_HEAD + STAT_PER_HEAD));
    if (nh_chunk < 1) nh_chunk = 1;
    if (nh_chunk > 6) nh_chunk = 6;
    float2* stats = (float2*)(ws + WS_SC + (size_t)nh_chunk * W16_PER_HEAD);

    lam_kernel<<<1, 128, 0, stream>>>(lq1, lk1, lq2, lk2, lam);

    proj_all<<<dim3(192, 10), 256, 0, stream>>>(
        q_r, q_i, k_r, k_i, v_r, v_i, pe_q_r, pe_q_i, pe_k_r, pe_k_i,
        qw_r, qw_i, qb_r, qb_i, kw_r, kw_i, kb_r, kb_i,
        vw_r, vw_i, vb_r, vb_i, gw_r, gw_i, gb_r, gb_i,
        qp_r, qp_i, kp_r, kp_i, vpT_r, vpT_i, gp_r, gp_i);

    for (int h0 = 0; h0 < H; h0 += nh_chunk) {
        int nhh = (H - h0 < nh_chunk) ? (H - h0) : nh_chunk;
        score_mfma<<<dim3(16, 8, nhh * 2), 256, 0, stream>>>(qp_r, qp_i, kp_r, kp_i, w16, h0);
        smstats<<<nhh * 2 * S, 256, 0, stream>>>(w16, stats);
        av_mfma<<<dim3(32, 2, nhh), 256, 0, stream>>>(w16, stats, vpT_r, vpT_i, acat_r, acat_i, h0);
    }

    rmsgate_kernel<<<NROWS, 256, 0, stream>>>(acat_r, acat_i, sub_w, lam, gp_r, gp_i);

    oproj_mfma<<<dim3(192, 2), 256, 0, stream>>>(gp_r, gp_i, ow_r, ow_i, ob_r, ob_i, out_r, out_i);
}

// Round 9
// 303.523 us; speedup vs baseline: 1.0583x; 1.0583x over previous
//
#include <hip/hip_runtime.h>
#include <hip/hip_cooperative_groups.h>
#include <math.h>

namespace cg = cooperative_groups;

#define H 12
#define S 1024
#define D 128
#define NROWS (H * S) // 12288

typedef __attribute__((ext_vector_type(8))) _Float16 f16x8; // 8 fp16 in 4 VGPRs
typedef __attribute__((ext_vector_type(4))) float f32x4;
typedef __attribute__((ext_vector_type(4))) int i32x4;

__device__ __forceinline__ short f2h(float f) {
    _Float16 h = (_Float16)f;
    return __builtin_bit_cast(short, h);
}
__device__ __forceinline__ float h2f(short s) {
    return (float)__builtin_bit_cast(_Float16, s);
}
__device__ __forceinline__ f16x8 fneg8(f16x8 v) {
    i32x4 u = __builtin_bit_cast(i32x4, v);
    u ^= (int)0x80008000;
    return __builtin_bit_cast(f16x8, u);
}

// ---- workspace layout (BYTE offsets) ----
#define WS_QP_R   0ULL
#define WS_QP_I   6291456ULL
#define WS_KP_R   12582912ULL
#define WS_KP_I   15728640ULL
#define WS_VPT_R  18874368ULL
#define WS_VPT_I  22020096ULL
#define WS_GP_R   25165824ULL
#define WS_GP_I   28311552ULL
#define WS_ACAT_R 31457280ULL
#define WS_ACAT_I 37748736ULL
#define WS_LAM    44040192ULL
#define WS_SC     44040448ULL
#define W16_PER_HEAD   4194304ULL // 2*1024*1024*2B
#define STAT_PER_HEAD  16384ULL   // 2*1024*8B
#define WS_STATS_FULL  (WS_SC + 12ULL * W16_PER_HEAD)          // 94372096
#define WS_NEED_FULL   (WS_STATS_FULL + 24576ULL * 8ULL)       // ~94.6MB

struct MegaParams {
    const float *q_r, *q_i, *k_r, *k_i, *v_r, *v_i;
    const float *pe_q_r, *pe_q_i, *pe_k_r, *pe_k_i;
    const float *qw_r, *qw_i, *qb_r, *qb_i;
    const float *kw_r, *kw_i, *kb_r, *kb_i;
    const float *vw_r, *vw_i, *vb_r, *vb_i;
    const float *gw_r, *gw_i, *gb_r, *gb_i;
    const float *ow_r, *ow_i, *ob_r, *ob_i;
    const float *lq1, *lk1, *lq2, *lk2, *sub_w;
    short *qp_r, *qp_i, *kp_r, *kp_i, *vpT_r, *vpT_i, *gp_r, *gp_i;
    short *acat_r, *acat_i;
    short *w16;
    float *lam;
    float2 *stats;
    float *out_r, *out_i;
};

// ============================================================
// dev_proj: exact r1-proven proj_all body (bxx,y = old blockIdx.x/.y)
// ============================================================
__device__ __forceinline__ void dev_proj(int bxx, int y, short* As, short* Brs, short* Bis,
                                         const MegaParams& P)
{
    const float *xr, *xi, *wr, *wi, *br, *bi, *per = nullptr, *pei = nullptr;
    short *outr_, *outi_;
    int M, omode, col0;
    if (y < 4)      { xr = P.q_r; xi = P.q_i; wr = P.qw_r; wi = P.qw_i; br = P.qb_r; bi = P.qb_i;
                      per = P.pe_q_r; pei = P.pe_q_i; outr_ = P.qp_r; outi_ = P.qp_i;
                      M = 256; omode = 1; col0 = y * 64; }
    else if (y < 6) { xr = P.k_r; xi = P.k_i; wr = P.kw_r; wi = P.kw_i; br = P.kb_r; bi = P.kb_i;
                      per = P.pe_k_r; pei = P.pe_k_i; outr_ = P.kp_r; outi_ = P.kp_i;
                      M = 128; omode = 1; col0 = (y - 4) * 64; }
    else if (y < 8) { xr = P.v_r; xi = P.v_i; wr = P.vw_r; wi = P.vw_i; br = P.vb_r; bi = P.vb_i;
                      outr_ = P.vpT_r; outi_ = P.vpT_i;
                      M = 128; omode = 2; col0 = (y - 6) * 64; }
    else            { xr = P.q_r; xi = P.q_i; wr = P.gw_r; wi = P.gw_i; br = P.gb_r; bi = P.gb_i;
                      outr_ = P.gp_r; outi_ = P.gp_i;
                      M = 128; omode = 1; col0 = (y - 8) * 64; }

    const int t = threadIdx.x;
    const int row0 = bxx * 64;
    const int lane = t & 63, wid = t >> 6;
    const int wm = (wid >> 1) * 32, wn = (wid & 1) * 32;
    const int fm = lane & 15, fq = lane >> 4;
    f32x4 zero4 = {0.f, 0.f, 0.f, 0.f};
    f32x4 accr[2][2], acci[2][2];
    #pragma unroll
    for (int i = 0; i < 2; ++i)
        #pragma unroll
        for (int j = 0; j < 2; ++j) { accr[i][j] = zero4; acci[i][j] = zero4; }

    for (int c = 0; c < 4; ++c) {
        const bool hi = (c >= 2);
        const int kb = (c & 1) * 64;
        const float* Asrc = hi ? xi : xr;
        const float* Brsrc = hi ? wi : wr;
        const float* Bisrc = hi ? wr : wi;
        const float bsign = hi ? -1.0f : 1.0f;
        __syncthreads();
        #pragma unroll
        for (int it = 0; it < 4; ++it) {
            int lin = it * 256 + t;
            int r = lin >> 4, k4 = (lin & 15) * 4;
            float4 va = *(const float4*)&Asrc[(size_t)(row0 + r) * 128 + kb + k4];
            *(short4*)&As[r * 72 + k4] = make_short4(f2h(va.x), f2h(va.y), f2h(va.z), f2h(va.w));
            float4 vr = *(const float4*)&Brsrc[(size_t)(col0 + r) * 128 + kb + k4];
            *(short4*)&Brs[r * 72 + k4] = make_short4(f2h(bsign * vr.x), f2h(bsign * vr.y),
                                                      f2h(bsign * vr.z), f2h(bsign * vr.w));
            float4 vi = *(const float4*)&Bisrc[(size_t)(col0 + r) * 128 + kb + k4];
            *(short4*)&Bis[r * 72 + k4] = make_short4(f2h(vi.x), f2h(vi.y), f2h(vi.z), f2h(vi.w));
        }
        __syncthreads();
        #pragma unroll
        for (int ks = 0; ks < 64; ks += 32) {
            f16x8 bfr[2], bfi[2];
            #pragma unroll
            for (int j = 0; j < 2; ++j) {
                bfr[j] = *(const f16x8*)&Brs[(wn + j * 16 + fm) * 72 + ks + fq * 8];
                bfi[j] = *(const f16x8*)&Bis[(wn + j * 16 + fm) * 72 + ks + fq * 8];
            }
            #pragma unroll
            for (int i = 0; i < 2; ++i) {
                f16x8 a = *(const f16x8*)&As[(wm + i * 16 + fm) * 72 + ks + fq * 8];
                #pragma unroll
                for (int j = 0; j < 2; ++j) {
                    accr[i][j] = __builtin_amdgcn_mfma_f32_16x16x32_f16(a, bfr[j], accr[i][j], 0, 0, 0);
                    acci[i][j] = __builtin_amdgcn_mfma_f32_16x16x32_f16(a, bfi[j], acci[i][j], 0, 0, 0);
                }
            }
        }
    }
    #pragma unroll
    for (int i = 0; i < 2; ++i)
        #pragma unroll
        for (int j = 0; j < 2; ++j) {
            int colc = col0 + wn + j * 16 + fm;
            float bbr = br[colc], bbi = bi[colc];
            if (omode == 2) {
                int rb = row0 + wm + i * 16 + fq * 4;
                int hq = rb >> 10, sq = rb & 1023;
                short4 o_r4 = make_short4(f2h(accr[i][j][0] + bbr), f2h(accr[i][j][1] + bbr),
                                          f2h(accr[i][j][2] + bbr), f2h(accr[i][j][3] + bbr));
                short4 o_i4 = make_short4(f2h(acci[i][j][0] + bbi), f2h(acci[i][j][1] + bbi),
                                          f2h(acci[i][j][2] + bbi), f2h(acci[i][j][3] + bbi));
                size_t ob = ((size_t)(hq * 128 + colc)) * 1024 + sq;
                *(short4*)&outr_[ob] = o_r4;
                *(short4*)&outi_[ob] = o_i4;
            } else {
                #pragma unroll
                for (int reg = 0; reg < 4; ++reg) {
                    int rr = row0 + wm + i * 16 + fq * 4 + reg;
                    float o_r = accr[i][j][reg] + bbr;
                    float o_i = acci[i][j][reg] + bbi;
                    if (per) {
                        o_r += per[(size_t)rr * 128 + (colc & 127)];
                        o_i += pei[(size_t)rr * 128 + (colc & 127)];
                    }
                    outr_[(size_t)rr * M + colc] = f2h(o_r);
                    outi_[(size_t)rr * M + colc] = f2h(o_i);
                }
            }
        }
}

// ============================================================
// dev_score: exact r1-proven score body. hhL = w16/local head idx,
// map = 0/1, h = global head for qp/kp reads.
// ============================================================
__device__ __forceinline__ void dev_score(int bxx, int byy, int hhL, int map, int h,
                                          short* Qr, short* Qi, short* Kt,
                                          const MegaParams& P, short* w16)
{
    const int t = threadIdx.x;
    const int q0 = bxx * 64, c0 = byy * 128;
    const int lane = t & 63, wid = t >> 6;
    const int wm = (wid >> 1) * 32, wn = (wid & 1) * 64;
    const int fm = lane & 15, fq = lane >> 4;
    f32x4 zero4 = {0.f, 0.f, 0.f, 0.f};
    f32x4 sr[2][4], si[2][4];
    #pragma unroll
    for (int i = 0; i < 2; ++i)
        #pragma unroll
        for (int j = 0; j < 4; ++j) { sr[i][j] = zero4; si[i][j] = zero4; }

    for (int kb = 0; kb < 2; ++kb) {
        const int kbase = map * 128 + kb * 64;
        __syncthreads();
        #pragma unroll
        for (int i = 0; i < 4; ++i) {
            int lin = i * 256 + t;
            int r = lin >> 4, k4 = (lin & 15) * 4;
            size_t qb = (size_t)(h * S + q0 + r) * 256 + kbase + k4;
            *(short4*)&Qr[r * 72 + k4] = *(const short4*)&P.qp_r[qb];
            *(short4*)&Qi[r * 72 + k4] = *(const short4*)&P.qp_i[qb];
        }
        #pragma unroll
        for (int i = 0; i < 8; ++i) {
            int lin = i * 256 + t;
            int r = lin >> 4, k4 = (lin & 15) * 4;
            *(short4*)&Kt[r * 72 + k4] =
                *(const short4*)&P.kp_r[(size_t)(h * S + c0 + r) * 128 + kb * 64 + k4];
        }
        __syncthreads();
        f16x8 aR[2][2], aI[2][2]; // [ks][i]
        #pragma unroll
        for (int ks = 0; ks < 2; ++ks)
            #pragma unroll
            for (int i = 0; i < 2; ++i) {
                int ao = (wm + i * 16 + fm) * 72 + ks * 32 + fq * 8;
                aR[ks][i] = *(const f16x8*)&Qr[ao];
                aI[ks][i] = *(const f16x8*)&Qi[ao];
            }
        #pragma unroll
        for (int ks = 0; ks < 2; ++ks) {
            f16x8 b[4];
            #pragma unroll
            for (int j = 0; j < 4; ++j)
                b[j] = *(const f16x8*)&Kt[(wn + j * 16 + fm) * 72 + ks * 32 + fq * 8];
            #pragma unroll
            for (int i = 0; i < 2; ++i)
                #pragma unroll
                for (int j = 0; j < 4; ++j) {
                    sr[i][j] = __builtin_amdgcn_mfma_f32_16x16x32_f16(aR[ks][i], b[j], sr[i][j], 0, 0, 0);
                    si[i][j] = __builtin_amdgcn_mfma_f32_16x16x32_f16(aI[ks][i], b[j], si[i][j], 0, 0, 0);
                }
        }
        __syncthreads();
        #pragma unroll
        for (int i = 0; i < 8; ++i) {
            int lin = i * 256 + t;
            int r = lin >> 4, k4 = (lin & 15) * 4;
            *(short4*)&Kt[r * 72 + k4] =
                *(const short4*)&P.kp_i[(size_t)(h * S + c0 + r) * 128 + kb * 64 + k4];
        }
        __syncthreads();
        #pragma unroll
        for (int ks = 0; ks < 2; ++ks) {
            f16x8 b[4];
            #pragma unroll
            for (int j = 0; j < 4; ++j)
                b[j] = *(const f16x8*)&Kt[(wn + j * 16 + fm) * 72 + ks * 32 + fq * 8];
            f16x8 nR0 = fneg8(aR[ks][0]), nR1 = fneg8(aR[ks][1]);
            #pragma unroll
            for (int j = 0; j < 4; ++j) {
                sr[0][j] = __builtin_amdgcn_mfma_f32_16x16x32_f16(aI[ks][0], b[j], sr[0][j], 0, 0, 0);
                si[0][j] = __builtin_amdgcn_mfma_f32_16x16x32_f16(nR0, b[j], si[0][j], 0, 0, 0);
                sr[1][j] = __builtin_amdgcn_mfma_f32_16x16x32_f16(aI[ks][1], b[j], sr[1][j], 0, 0, 0);
                si[1][j] = __builtin_amdgcn_mfma_f32_16x16x32_f16(nR1, b[j], si[1][j], 0, 0, 0);
            }
        }
    }
    const float scale = 0.08838834764831845f;
    #pragma unroll
    for (int i = 0; i < 2; ++i)
        #pragma unroll
        for (int j = 0; j < 4; ++j) {
            int kcol = c0 + wn + j * 16 + fm;
            #pragma unroll
            for (int reg = 0; reg < 4; ++reg) {
                int q = q0 + wm + i * 16 + fq * 4 + reg;
                float r1 = sr[i][j][reg], I1 = si[i][j][reg];
                float m1 = sqrtf(fmaf(r1, r1, fmaf(I1, I1, 1e-8f))) * scale;
                w16[(((size_t)hhL * 2 + map) * S + q) * S + kcol] = f2h(m1);
            }
        }
}

// ============================================================
// dev_av: exact r1-proven av body. hhL indexes w16/stats, h global head.
// ============================================================
__device__ __forceinline__ void dev_av(int bxx, int comp, int hhL, int h,
                                       short* W1, short* W2, short* Vc,
                                       const MegaParams& P, const short* w16,
                                       const float2* stats)
{
    const int t = threadIdx.x;
    const int q0 = bxx * 32;
    const short* vpT = comp ? P.vpT_i : P.vpT_r;
    short* acat = comp ? P.acat_i : P.acat_r;
    const float2* st1 = stats + ((size_t)hhL * 2 + 0) * S;
    const float2* st2 = stats + ((size_t)hhL * 2 + 1) * S;
    const int lane = t & 63, wid = t >> 6;
    const int wm = (wid >> 1) * 16, wn = (wid & 1) * 64;
    const int fm = lane & 15, fq = lane >> 4;
    f32x4 zero4 = {0.f, 0.f, 0.f, 0.f};
    f32x4 a1[4], a2[4];
    #pragma unroll
    for (int j = 0; j < 4; ++j) { a1[j] = zero4; a2[j] = zero4; }

    for (int k0 = 0; k0 < S; k0 += 64) {
        __syncthreads();
        #pragma unroll
        for (int it = 0; it < 2; ++it) {
            int lin = it * 256 + t;
            int r = lin >> 4, k4 = (lin & 15) * 4;
            float2 s1v = st1[q0 + r];
            float2 s2v = st2[q0 + r];
            short4 m1 = *(const short4*)&w16[(((size_t)hhL * 2 + 0) * S + q0 + r) * S + k0 + k4];
            short4 m2 = *(const short4*)&w16[(((size_t)hhL * 2 + 1) * S + q0 + r) * S + k0 + k4];
            *(short4*)&W1[r * 72 + k4] = make_short4(
                f2h(__expf(h2f(m1.x) - s1v.x) * s1v.y), f2h(__expf(h2f(m1.y) - s1v.x) * s1v.y),
                f2h(__expf(h2f(m1.z) - s1v.x) * s1v.y), f2h(__expf(h2f(m1.w) - s1v.x) * s1v.y));
            *(short4*)&W2[r * 72 + k4] = make_short4(
                f2h(__expf(h2f(m2.x) - s2v.x) * s2v.y), f2h(__expf(h2f(m2.y) - s2v.x) * s2v.y),
                f2h(__expf(h2f(m2.z) - s2v.x) * s2v.y), f2h(__expf(h2f(m2.w) - s2v.x) * s2v.y));
        }
        #pragma unroll
        for (int it = 0; it < 8; ++it) {
            int lin = it * 256 + t;
            int dd = lin >> 4, k4 = (lin & 15) * 4;
            *(short4*)&Vc[dd * 72 + k4] = *(const short4*)&vpT[(size_t)(h * 128 + dd) * 1024 + k0 + k4];
        }
        __syncthreads();
        #pragma unroll
        for (int ks = 0; ks < 64; ks += 32) {
            f16x8 b[4];
            #pragma unroll
            for (int j = 0; j < 4; ++j)
                b[j] = *(const f16x8*)&Vc[(wn + j * 16 + fm) * 72 + ks + fq * 8];
            int wo = (wm + fm) * 72 + ks + fq * 8;
            f16x8 w1f = *(const f16x8*)&W1[wo];
            f16x8 w2f = *(const f16x8*)&W2[wo];
            #pragma unroll
            for (int j = 0; j < 4; ++j) {
                a1[j] = __builtin_amdgcn_mfma_f32_16x16x32_f16(w1f, b[j], a1[j], 0, 0, 0);
                a2[j] = __builtin_amdgcn_mfma_f32_16x16x32_f16(w2f, b[j], a2[j], 0, 0, 0);
            }
        }
    }
    #pragma unroll
    for (int j = 0; j < 4; ++j) {
        int d = wn + j * 16 + fm;
        #pragma unroll
        for (int reg = 0; reg < 4; ++reg) {
            int q = q0 + wm + fq * 4 + reg;
            size_t rowb = (size_t)(h * S + q) * 256;
            acat[rowb + d]       = f2h(a1[j][reg]);
            acat[rowb + 128 + d] = f2h(a2[j][reg]);
        }
    }
}

// ============================================================
// dev_oproj: exact r1-proven oproj body.
// ============================================================
__device__ __forceinline__ void dev_oproj(int bxx, int byy, short* As, short* Brs, short* Bis,
                                          const MegaParams& P)
{
    const int t = threadIdx.x;
    const int row0 = bxx * 64, col0 = byy * 64;
    const int lane = t & 63, wid = t >> 6;
    const int wm = (wid >> 1) * 32, wn = (wid & 1) * 32;
    const int fm = lane & 15, fq = lane >> 4;
    f32x4 zero4 = {0.f, 0.f, 0.f, 0.f};
    f32x4 accr[2][2], acci[2][2];
    #pragma unroll
    for (int i = 0; i < 2; ++i)
        #pragma unroll
        for (int j = 0; j < 2; ++j) { accr[i][j] = zero4; acci[i][j] = zero4; }

    for (int c = 0; c < 4; ++c) {
        const bool hi = (c >= 2);
        const int kb = (c & 1) * 64;
        const short* Asrc = hi ? P.gp_i : P.gp_r;
        const float* Brsrc = hi ? P.ow_i : P.ow_r;
        const float* Bisrc = hi ? P.ow_r : P.ow_i;
        const float bsign = hi ? -1.0f : 1.0f;
        __syncthreads();
        #pragma unroll
        for (int it = 0; it < 4; ++it) {
            int lin = it * 256 + t;
            int r = lin >> 4, k4 = (lin & 15) * 4;
            *(short4*)&As[r * 72 + k4] = *(const short4*)&Asrc[(size_t)(row0 + r) * 128 + kb + k4];
            float4 vr = *(const float4*)&Brsrc[(size_t)(col0 + r) * 128 + kb + k4];
            *(short4*)&Brs[r * 72 + k4] = make_short4(f2h(bsign * vr.x), f2h(bsign * vr.y),
                                                      f2h(bsign * vr.z), f2h(bsign * vr.w));
            float4 vi = *(const float4*)&Bisrc[(size_t)(col0 + r) * 128 + kb + k4];
            *(short4*)&Bis[r * 72 + k4] = make_short4(f2h(vi.x), f2h(vi.y), f2h(vi.z), f2h(vi.w));
        }
        __syncthreads();
        #pragma unroll
        for (int ks = 0; ks < 64; ks += 32) {
            f16x8 bfr[2], bfi[2];
            #pragma unroll
            for (int j = 0; j < 2; ++j) {
                bfr[j] = *(const f16x8*)&Brs[(wn + j * 16 + fm) * 72 + ks + fq * 8];
                bfi[j] = *(const f16x8*)&Bis[(wn + j * 16 + fm) * 72 + ks + fq * 8];
            }
            #pragma unroll
            for (int i = 0; i < 2; ++i) {
                f16x8 a = *(const f16x8*)&As[(wm + i * 16 + fm) * 72 + ks + fq * 8];
                #pragma unroll
                for (int j = 0; j < 2; ++j) {
                    accr[i][j] = __builtin_amdgcn_mfma_f32_16x16x32_f16(a, bfr[j], accr[i][j], 0, 0, 0);
                    acci[i][j] = __builtin_amdgcn_mfma_f32_16x16x32_f16(a, bfi[j], acci[i][j], 0, 0, 0);
                }
            }
        }
    }
    #pragma unroll
    for (int i = 0; i < 2; ++i)
        #pragma unroll
        for (int j = 0; j < 2; ++j) {
            int colc = col0 + wn + j * 16 + fm;
            float bbr = P.ob_r[colc], bbi = P.ob_i[colc];
            #pragma unroll
            for (int reg = 0; reg < 4; ++reg) {
                int rr = row0 + wm + i * 16 + fq * 4 + reg;
                P.out_r[(size_t)rr * 128 + colc] = accr[i][j][reg] + bbr;
                P.out_i[(size_t)rr * 128 + colc] = acci[i][j][reg] + bbi;
            }
        }
}

// ============================================================
// MEGA: all phases in ONE cooperative kernel. grid-stride phases with
// grid.sync() between; bodies are the proven dev_* functions.
// smstats/rmsgate rewritten per-wave (no barriers, 16 rows in flight/CU).
// LDS: 36864B (score phase) -> 4 blocks/CU -> 1024 co-resident blocks.
// ============================================================
__global__ __launch_bounds__(256) void mega(MegaParams P)
{
    cg::grid_group gg = cg::this_grid();
    __shared__ __align__(16) char SM[36864];
    const int nb = (int)gridDim.x, bid = (int)blockIdx.x;
    const int t = threadIdx.x, lane = t & 63, wid = t >> 6;

    // ---- P0: lam (all blocks compute; block 0 writes) ----
    {
        float p1 = (t < 128) ? P.lq1[t] * P.lk1[t] : 0.f;
        float p2 = (t < 128) ? P.lq2[t] * P.lk2[t] : 0.f;
        #pragma unroll
        for (int off = 32; off; off >>= 1) {
            p1 += __shfl_xor(p1, off);
            p2 += __shfl_xor(p2, off);
        }
        float* s1 = (float*)SM;
        float* s2 = s1 + 4;
        if ((t & 63) == 0) { s1[wid] = p1; s2[wid] = p2; }
        __syncthreads();
        if (bid == 0 && t == 0) {
            float l1 = expf(s1[0] + s1[1] + s1[2] + s1[3]);
            float l2 = expf(s2[0] + s2[1] + s2[2] + s2[3]);
            float x = l1 - l2 + 0.3555090675909693f;
            P.lam[0] = 1.0f / (1.0f + expf(-x));
        }
        __syncthreads();
    }

    // ---- P1: projections (1920 items) ----
    {
        short* As = (short*)SM;
        short* Brs = As + 64 * 72;
        short* Bis = Brs + 64 * 72;
        for (int it = bid; it < 1920; it += nb)
            dev_proj(it % 192, it / 192, As, Brs, Bis, P);
    }
    gg.sync();

    // ---- P2: scores (3072 items) ----
    {
        short* Qr = (short*)SM;
        short* Qi = Qr + 64 * 72;
        short* Kt = Qi + 64 * 72;
        for (int it = bid; it < 3072; it += nb) {
            int z = it / 128;
            dev_score(it % 16, (it / 16) % 8, z >> 1, z & 1, z >> 1, Qr, Qi, Kt, P, P.w16);
        }
    }
    gg.sync();

    // ---- P3: softmax stats, per-wave (24576 rows) ----
    for (int row = bid * 4 + wid; row < 2 * NROWS; row += nb * 4) {
        const short* rp = P.w16 + (size_t)row * S;
        short4 v0 = ((const short4*)rp)[lane];
        short4 v1 = ((const short4*)rp)[lane + 64];
        short4 v2 = ((const short4*)rp)[lane + 128];
        short4 v3 = ((const short4*)rp)[lane + 192];
        float f[16] = {h2f(v0.x), h2f(v0.y), h2f(v0.z), h2f(v0.w),
                       h2f(v1.x), h2f(v1.y), h2f(v1.z), h2f(v1.w),
                       h2f(v2.x), h2f(v2.y), h2f(v2.z), h2f(v2.w),
                       h2f(v3.x), h2f(v3.y), h2f(v3.z), h2f(v3.w)};
        float m = f[0];
        #pragma unroll
        for (int j = 1; j < 16; ++j) m = fmaxf(m, f[j]);
        #pragma unroll
        for (int off = 32; off; off >>= 1) m = fmaxf(m, __shfl_xor(m, off));
        float ssum = 0.f;
        #pragma unroll
        for (int j = 0; j < 16; ++j) ssum += __expf(f[j] - m);
        #pragma unroll
        for (int off = 32; off; off >>= 1) ssum += __shfl_xor(ssum, off);
        if (lane == 0) P.stats[row] = make_float2(m, 1.0f / ssum);
    }
    gg.sync();

    // ---- P4: AV (768 items) ----
    {
        short* W1 = (short*)SM;
        short* W2 = W1 + 32 * 72;
        short* Vc = W2 + 32 * 72;
        for (int it = bid; it < 768; it += nb)
            dev_av(it % 32, (it / 32) % 2, it / 64, it / 64, W1, W2, Vc, P, P.w16, P.stats);
    }
    gg.sync();

    // ---- P5: rmsgate, per-wave (12288 rows) ----
    {
        const float lam = P.lam[0];
        for (int row = bid * 4 + wid; row < NROWS; row += nb * 4) {
            short4 ar4 = ((const short4*)(P.acat_r + (size_t)row * 256))[lane];
            short4 ai4 = ((const short4*)(P.acat_i + (size_t)row * 256))[lane];
            float ar[4] = {h2f(ar4.x), h2f(ar4.y), h2f(ar4.z), h2f(ar4.w)};
            float ai[4] = {h2f(ai4.x), h2f(ai4.y), h2f(ai4.z), h2f(ai4.w)};
            float ss = 0.f;
            #pragma unroll
            for (int j = 0; j < 4; ++j) ss = fmaf(ar[j], ar[j], fmaf(ai[j], ai[j], ss));
            #pragma unroll
            for (int off = 32; off; off >>= 1) ss += __shfl_xor(ss, off);
            float inv_rms = 1.0f / sqrtf(ss * (1.0f / 256.0f) + 1e-5f);
            float4 sw = ((const float4*)P.sub_w)[lane];
            float Cr[4], Ci[4];
            Cr[0] = ar[0] * inv_rms * sw.x; Ci[0] = ai[0] * inv_rms * sw.x;
            Cr[1] = ar[1] * inv_rms * sw.y; Ci[1] = ai[1] * inv_rms * sw.y;
            Cr[2] = ar[2] * inv_rms * sw.z; Ci[2] = ai[2] * inv_rms * sw.z;
            Cr[3] = ar[3] * inv_rms * sw.w; Ci[3] = ai[3] * inv_rms * sw.w;
            float pr[4], pi[4];
            #pragma unroll
            for (int j = 0; j < 4; ++j) {
                pr[j] = __shfl_xor(Cr[j], 32);
                pi[j] = __shfl_xor(Ci[j], 32);
            }
            if (lane < 32) { // lanes 0..31 own elems 0..127
                short4 gr4 = ((const short4*)(P.gp_r + (size_t)row * 128))[lane];
                short4 gi4 = ((const short4*)(P.gp_i + (size_t)row * 128))[lane];
                float grv[4] = {h2f(gr4.x), h2f(gr4.y), h2f(gr4.z), h2f(gr4.w)};
                float giv[4] = {h2f(gi4.x), h2f(gi4.y), h2f(gi4.z), h2f(gi4.w)};
                short orx[4], oix[4];
                #pragma unroll
                for (int j = 0; j < 4; ++j) {
                    float o_r = Cr[j] - lam * pr[j];
                    float o_i = Ci[j] - lam * pi[j];
                    orx[j] = f2h(grv[j] * o_r - giv[j] * o_i);
                    oix[j] = f2h(grv[j] * o_i + giv[j] * o_r);
                }
                ((short4*)(P.gp_r + (size_t)row * 128))[lane] = make_short4(orx[0], orx[1], orx[2], orx[3]);
                ((short4*)(P.gp_i + (size_t)row * 128))[lane] = make_short4(oix[0], oix[1], oix[2], oix[3]);
            }
        }
    }
    gg.sync();

    // ---- P6: o-projection (384 items) ----
    {
        short* As = (short*)SM;
        short* Brs = As + 64 * 72;
        short* Bis = Brs + 64 * 72;
        for (int it = bid; it < 384; it += nb)
            dev_oproj(it % 192, it / 192, As, Brs, Bis, P);
    }
}

// ============================================================
// FALLBACK kernels (exact r1 pipeline via the same dev_* bodies)
// ============================================================
__global__ void lam_k(MegaParams P)
{
    int t = threadIdx.x; // 128 threads
    float p1 = P.lq1[t] * P.lk1[t];
    float p2 = P.lq2[t] * P.lk2[t];
    #pragma unroll
    for (int off = 32; off; off >>= 1) {
        p1 += __shfl_xor(p1, off);
        p2 += __shfl_xor(p2, off);
    }
    __shared__ float s1[2], s2[2];
    if ((t & 63) == 0) { s1[t >> 6] = p1; s2[t >> 6] = p2; }
    __syncthreads();
    if (t == 0) {
        float l1 = expf(s1[0] + s1[1]);
        float l2 = expf(s2[0] + s2[1]);
        float x = l1 - l2 + 0.3555090675909693f;
        P.lam[0] = 1.0f / (1.0f + expf(-x));
    }
}

__global__ __launch_bounds__(256) void proj_k(MegaParams P)
{
    __shared__ short As[64 * 72], Brs[64 * 72], Bis[64 * 72];
    dev_proj(blockIdx.x, blockIdx.y, As, Brs, Bis, P);
}

__global__ __launch_bounds__(256) void score_k(MegaParams P, int h0)
{
    __shared__ short Qr[64 * 72], Qi[64 * 72], Kt[128 * 72];
    int z = blockIdx.z;
    dev_score(blockIdx.x, blockIdx.y, z >> 1, z & 1, h0 + (z >> 1), Qr, Qi, Kt, P, P.w16);
}

__global__ __launch_bounds__(256) void smstats_k(MegaParams P, float2* stats)
{
    const short* row = P.w16 + (size_t)blockIdx.x * S;
    int t = threadIdx.x;
    short4 s = ((const short4*)row)[t];
    float f0 = h2f(s.x), f1 = h2f(s.y), f2v = h2f(s.z), f3 = h2f(s.w);
    float m = fmaxf(fmaxf(f0, f1), fmaxf(f2v, f3));
    #pragma unroll
    for (int off = 32; off; off >>= 1) m = fmaxf(m, __shfl_xor(m, off));
    __shared__ float redm[4], reds[4];
    int w = t >> 6;
    if ((t & 63) == 0) redm[w] = m;
    __syncthreads();
    m = fmaxf(fmaxf(redm[0], redm[1]), fmaxf(redm[2], redm[3]));
    float ssum = __expf(f0 - m) + __expf(f1 - m) + __expf(f2v - m) + __expf(f3 - m);
    #pragma unroll
    for (int off = 32; off; off >>= 1) ssum += __shfl_xor(ssum, off);
    if ((t & 63) == 0) reds[w] = ssum;
    __syncthreads();
    if (t == 0) {
        float total = reds[0] + reds[1] + reds[2] + reds[3];
        stats[blockIdx.x] = make_float2(m, 1.0f / total);
    }
}

__global__ __launch_bounds__(256) void av_k(MegaParams P, float2* stats, int h0)
{
    __shared__ short W1[32 * 72], W2[32 * 72], Vc[128 * 72];
    dev_av(blockIdx.x, blockIdx.y, blockIdx.z, h0 + blockIdx.z, W1, W2, Vc, P, P.w16, stats);
}

__global__ __launch_bounds__(256) void rmsgate_k(MegaParams P)
{
    int row = blockIdx.x;
    int t = threadIdx.x;
    float ar = h2f(P.acat_r[(size_t)row * 256 + t]);
    float ai = h2f(P.acat_i[(size_t)row * 256 + t]);
    float ss = fmaf(ar, ar, ai * ai);
    #pragma unroll
    for (int off = 32; off; off >>= 1) ss += __shfl_xor(ss, off);
    __shared__ float red[4];
    if ((t & 63) == 0) red[t >> 6] = ss;
    __syncthreads();
    float total = red[0] + red[1] + red[2] + red[3];
    float inv_rms = 1.0f / sqrtf(total * (1.0f / 256.0f) + 1e-5f);
    float sw = P.sub_w[t];
    __shared__ float Cr[256], Ci[256];
    Cr[t] = ar * inv_rms * sw;
    Ci[t] = ai * inv_rms * sw;
    __syncthreads();
    if (t < 128) {
        float lam = P.lam[0];
        float o_r = Cr[t] - lam * Cr[t + 128];
        float o_i = Ci[t] - lam * Ci[t + 128];
        float gr = h2f(P.gp_r[(size_t)row * 128 + t]);
        float gi = h2f(P.gp_i[(size_t)row * 128 + t]);
        P.gp_r[(size_t)row * 128 + t] = f2h(gr * o_r - gi * o_i);
        P.gp_i[(size_t)row * 128 + t] = f2h(gr * o_i + gi * o_r);
    }
}

__global__ __launch_bounds__(256) void oproj_k(MegaParams P)
{
    __shared__ short As[64 * 72], Brs[64 * 72], Bis[64 * 72];
    dev_oproj(blockIdx.x, blockIdx.y, As, Brs, Bis, P);
}

// ============================================================
extern "C" void kernel_launch(void* const* d_in, const int* in_sizes, int n_in,
                              void* d_out, int out_size, void* d_ws, size_t ws_size,
                              hipStream_t stream)
{
    (void)in_sizes; (void)n_in; (void)out_size;
    char* ws = (char*)d_ws;

    MegaParams P;
    P.q_r    = (const float*)d_in[0];  P.q_i    = (const float*)d_in[1];
    P.k_r    = (const float*)d_in[2];  P.k_i    = (const float*)d_in[3];
    P.v_r    = (const float*)d_in[4];  P.v_i    = (const float*)d_in[5];
    P.pe_q_r = (const float*)d_in[6];  P.pe_q_i = (const float*)d_in[7];
    P.pe_k_r = (const float*)d_in[8];  P.pe_k_i = (const float*)d_in[9];
    P.qw_r   = (const float*)d_in[10]; P.qw_i   = (const float*)d_in[11];
    P.qb_r   = (const float*)d_in[12]; P.qb_i   = (const float*)d_in[13];
    P.kw_r   = (const float*)d_in[14]; P.kw_i   = (const float*)d_in[15];
    P.kb_r   = (const float*)d_in[16]; P.kb_i   = (const float*)d_in[17];
    P.vw_r   = (const float*)d_in[18]; P.vw_i   = (const float*)d_in[19];
    P.vb_r   = (const float*)d_in[20]; P.vb_i   = (const float*)d_in[21];
    P.gw_r   = (const float*)d_in[22]; P.gw_i   = (const float*)d_in[23];
    P.gb_r   = (const float*)d_in[24]; P.gb_i   = (const float*)d_in[25];
    P.ow_r   = (const float*)d_in[26]; P.ow_i   = (const float*)d_in[27];
    P.ob_r   = (const float*)d_in[28]; P.ob_i   = (const float*)d_in[29];
    P.lq1    = (const float*)d_in[30]; P.lk1    = (const float*)d_in[31];
    P.lq2    = (const float*)d_in[32]; P.lk2    = (const float*)d_in[33];
    P.sub_w  = (const float*)d_in[34];

    P.qp_r   = (short*)(ws + WS_QP_R);   P.qp_i   = (short*)(ws + WS_QP_I);
    P.kp_r   = (short*)(ws + WS_KP_R);   P.kp_i   = (short*)(ws + WS_KP_I);
    P.vpT_r  = (short*)(ws + WS_VPT_R);  P.vpT_i  = (short*)(ws + WS_VPT_I);
    P.gp_r   = (short*)(ws + WS_GP_R);   P.gp_i   = (short*)(ws + WS_GP_I);
    P.acat_r = (short*)(ws + WS_ACAT_R); P.acat_i = (short*)(ws + WS_ACAT_I);
    P.lam    = (float*)(ws + WS_LAM);
    P.w16    = (short*)(ws + WS_SC);
    P.stats  = (float2*)(ws + WS_STATS_FULL);
    P.out_r  = (float*)d_out;
    P.out_i  = P.out_r + (size_t)NROWS * D;

    // ---- cooperative mega path (requires full-size workspace) ----
    static int s_coopGrid = -2; // -2 untested, 0 disabled, >0 grid size
    if (s_coopGrid == -2) {
        int maxb = 0;
        hipError_t e = hipOccupancyMaxActiveBlocksPerMultiprocessor(&maxb, mega, 256, 0);
        s_coopGrid = (e == hipSuccess && maxb >= 1) ? maxb * 256 /*CUs*/ : 0;
        if (s_coopGrid > 2048) s_coopGrid = 2048;
    }
    if (s_coopGrid > 0 && ws_size >= WS_NEED_FULL) {
        void* args[] = {(void*)&P};
        hipError_t e = hipLaunchCooperativeKernel(mega, dim3(s_coopGrid), dim3(256),
                                                  args, 0, stream);
        if (e == hipSuccess) return;
        s_coopGrid = 0; // disable and fall through to classic path
    }

    // ---- fallback: exact r1 7-kernel pipeline ----
    size_t avail = ws_size > WS_SC ? ws_size - WS_SC : 0;
    int nh_chunk = (int)(avail / (W16_PER_HEAD + STAT_PER_HEAD));
    if (nh_chunk < 1) nh_chunk = 1;
    if (nh_chunk > H) nh_chunk = H;
    float2* stats = (float2*)(ws + WS_SC + (size_t)nh_chunk * W16_PER_HEAD);

    lam_k<<<1, 128, 0, stream>>>(P);
    proj_k<<<dim3(192, 10), 256, 0, stream>>>(P);
    for (int h0 = 0; h0 < H; h0 += nh_chunk) {
        int nhh = (H - h0 < nh_chunk) ? (H - h0) : nh_chunk;
        score_k<<<dim3(16, 8, nhh * 2), 256, 0, stream>>>(P, h0);
        smstats_k<<<nhh * 2 * S, 256, 0, stream>>>(P, stats);
        av_k<<<dim3(32, 2, nhh), 256, 0, stream>>>(P, stats, h0);
    }
    rmsgate_k<<<NROWS, 256, 0, stream>>>(P);
    oproj_k<<<dim3(192, 2), 256, 0, stream>>>(P);
}